// Round 1
// baseline (19435.599 us; speedup 1.0000x reference)
//
#include <hip/hip_runtime.h>
#include <hip/hip_cooperative_groups.h>
#include <cmath>

namespace cg = cooperative_groups;

#define ZD    4096
#define HID   1024
#define G3    3072
#define DN    100
#define OD    100
#define BB    8
#define WW    512
#define ROWS  4096   // B*W

// ---------------- fp32 GEMM: C[M,N] = A[M,K] @ B[K,N] + bias[N] ----------------
#define BM 64
#define BN 128
#define BK 16

__global__ __launch_bounds__(256) void gemm_f32(
    const float* __restrict__ A, const float* __restrict__ B,
    const float* __restrict__ bias, float* __restrict__ C,
    int M, int N, int K)
{
    __shared__ __align__(16) float As[BK][BM + 4];
    __shared__ __align__(16) float Bs[BK][BN + 4];
    const int tid = threadIdx.x;
    const int tx = tid & 15;        // -> m (4 rows)
    const int ty = tid >> 4;        // -> n (8 cols)
    const int bm0 = blockIdx.y * BM;
    const int bn0 = blockIdx.x * BN;

    float acc[4][8] = {};

    for (int k0 = 0; k0 < K; k0 += BK) {
        // A tile 64x16, store transposed
        {
            const int mr = tid >> 2;
            const int kc = (tid & 3) << 2;
            float4 av = *(const float4*)(A + (size_t)(bm0 + mr) * K + k0 + kc);
            As[kc + 0][mr] = av.x;
            As[kc + 1][mr] = av.y;
            As[kc + 2][mr] = av.z;
            As[kc + 3][mr] = av.w;
        }
        // B tile 16x128: 512 float4, 2 per thread
        #pragma unroll
        for (int i = 0; i < 2; ++i) {
            const int v = tid + (i << 8);
            const int kr = v >> 5;
            const int nc = (v & 31) << 2;
            *(float4*)&Bs[kr][nc] =
                *(const float4*)(B + (size_t)(k0 + kr) * N + bn0 + nc);
        }
        __syncthreads();
        #pragma unroll
        for (int kk = 0; kk < BK; ++kk) {
            float4 a  = *(const float4*)&As[kk][tx << 2];
            float4 b0 = *(const float4*)&Bs[kk][ty << 3];
            float4 b1 = *(const float4*)&Bs[kk][(ty << 3) + 4];
            const float av[4] = {a.x, a.y, a.z, a.w};
            const float bv[8] = {b0.x, b0.y, b0.z, b0.w, b1.x, b1.y, b1.z, b1.w};
            #pragma unroll
            for (int i = 0; i < 4; ++i)
                #pragma unroll
                for (int j = 0; j < 8; ++j)
                    acc[i][j] = fmaf(av[i], bv[j], acc[i][j]);
        }
        __syncthreads();
    }

    #pragma unroll
    for (int i = 0; i < 4; ++i) {
        const int row = bm0 + (tx << 2) + i;
        float* crow = C + (size_t)row * N + bn0 + (ty << 3);
        const float* brow = bias + bn0 + (ty << 3);
        float4 o0 = make_float4(acc[i][0] + brow[0], acc[i][1] + brow[1],
                                acc[i][2] + brow[2], acc[i][3] + brow[3]);
        float4 o1 = make_float4(acc[i][4] + brow[4], acc[i][5] + brow[5],
                                acc[i][6] + brow[6], acc[i][7] + brow[7]);
        *(float4*)crow = o0;
        *(float4*)(crow + 4) = o1;
    }
}

// ---------------- persistent cooperative GRU recurrence ----------------
// 256 blocks x 256 threads. Block owns 4 hidden units (nh), one per wave.
// Wave's 3 gate columns of W_hh live in registers: lane owns k = j*256 + lane*4 + q.
__global__ __launch_bounds__(256) void recur_kernel(
    const float* __restrict__ GI, const float* __restrict__ Whh,
    const float* __restrict__ bhh, float* __restrict__ Hall)
{
    __shared__ __align__(16) float hs[BB][HID];
    __shared__ float gh_s[4][BB][3];
    const int tid = threadIdx.x;
    const int lane = tid & 63;
    const int wv = tid >> 6;
    const int nh = blockIdx.x * 4 + wv;

    float wr0[16], wr1[16], wr2[16];
    #pragma unroll
    for (int j = 0; j < 4; ++j)
        #pragma unroll
        for (int q = 0; q < 4; ++q) {
            const int k = (j << 8) + (lane << 2) + q;
            const float* wrow = Whh + (size_t)k * G3;
            wr0[(j << 2) + q] = wrow[nh];
            wr1[(j << 2) + q] = wrow[HID + nh];
            wr2[(j << 2) + q] = wrow[2 * HID + nh];
        }

    // gate-thread (tid<32) constants
    float bh0 = 0.f, bh1 = 0.f, bh2 = 0.f;
    int g_nh = 0, g_b = 0;
    if (tid < 32) {
        g_nh = blockIdx.x * 4 + (tid >> 3);
        g_b  = tid & 7;
        bh0 = bhh[g_nh];
        bh1 = bhh[HID + g_nh];
        bh2 = bhh[2 * HID + g_nh];
    }

    for (int i = tid; i < BB * HID; i += 256) ((float*)hs)[i] = 0.f;
    cg::grid_group grid = cg::this_grid();
    __syncthreads();

    for (int t = 0; t < WW; ++t) {
        // prefetch gi for gate threads (independent of h)
        float gi_r = 0.f, gi_u = 0.f, gi_n = 0.f;
        if (tid < 32) {
            const size_t row = (size_t)g_b * WW + t;
            const float* gp = GI + row * G3;
            gi_r = gp[g_nh];
            gi_u = gp[HID + g_nh];
            gi_n = gp[2 * HID + g_nh];
        }
        if (t > 0) {
            const float4* hp = (const float4*)(Hall + (size_t)(t - 1) * (BB * HID));
            float4* hd = (float4*)hs;
            #pragma unroll
            for (int i = 0; i < 8; ++i) hd[tid + (i << 8)] = hp[tid + (i << 8)];
            __syncthreads();
        }
        // gh = h @ Whh for this wave's 3 columns
        #pragma unroll
        for (int b = 0; b < BB; ++b) {
            const float4* hb = (const float4*)&hs[b][0];
            float p0 = 0.f, p1 = 0.f, p2 = 0.f;
            #pragma unroll
            for (int j = 0; j < 4; ++j) {
                float4 h4 = hb[(j << 6) + lane];
                const float hv[4] = {h4.x, h4.y, h4.z, h4.w};
                #pragma unroll
                for (int q = 0; q < 4; ++q) {
                    p0 = fmaf(hv[q], wr0[(j << 2) + q], p0);
                    p1 = fmaf(hv[q], wr1[(j << 2) + q], p1);
                    p2 = fmaf(hv[q], wr2[(j << 2) + q], p2);
                }
            }
            #pragma unroll
            for (int m = 32; m >= 1; m >>= 1) {
                p0 += __shfl_xor(p0, m, 64);
                p1 += __shfl_xor(p1, m, 64);
                p2 += __shfl_xor(p2, m, 64);
            }
            if (lane == 0) {
                gh_s[wv][b][0] = p0;
                gh_s[wv][b][1] = p1;
                gh_s[wv][b][2] = p2;
            }
        }
        __syncthreads();
        if (tid < 32) {
            const int wi = tid >> 3;
            const float ghr = gh_s[wi][g_b][0] + bh0;
            const float ghu = gh_s[wi][g_b][1] + bh1;
            const float ghn = gh_s[wi][g_b][2] + bh2;
            const float r = 1.f / (1.f + expf(-(gi_r + ghr)));
            const float u = 1.f / (1.f + expf(-(gi_u + ghu)));
            const float n = tanhf(gi_n + r * ghn);
            const float hold = hs[g_b][g_nh];
            const float hnew = (1.f - u) * n + u * hold;
            Hall[(size_t)t * (BB * HID) + g_b * HID + g_nh] = hnew;
        }
        grid.sync();
    }
}

// ---------------- dense + heads + reparameterized sample ----------------
// 1024 blocks x 128 threads; each block does 4 consecutive timesteps of one batch.
__global__ __launch_bounds__(128) void head_kernel(
    const float* __restrict__ Hall, const float* __restrict__ Wd,
    const float* __restrict__ bd, const float* __restrict__ Wmu,
    const float* __restrict__ bmu, const float* __restrict__ Wsg,
    const float* __restrict__ bsg, const float* __restrict__ noise,
    float* __restrict__ out)
{
    const int blk = blockIdx.x;        // 0..1023
    const int b = blk >> 7;            // batch
    const int t0 = (blk & 127) << 2;   // 4 timesteps
    __shared__ __align__(16) float hsh[4][HID];
    __shared__ float dsh[4][DN];
    const int tid = threadIdx.x;

    #pragma unroll
    for (int rr = 0; rr < 4; ++rr) {
        const float4* hp = (const float4*)(Hall + (size_t)(t0 + rr) * (BB * HID) + (size_t)b * HID);
        ((float4*)hsh[rr])[tid] = hp[tid];
        ((float4*)hsh[rr])[tid + 128] = hp[tid + 128];
    }
    __syncthreads();

    if (tid < DN) {
        float a0 = bd[tid], a1 = bd[tid], a2 = bd[tid], a3 = bd[tid];
        for (int k = 0; k < HID; ++k) {
            const float wv = Wd[k * DN + tid];
            a0 = fmaf(hsh[0][k], wv, a0);
            a1 = fmaf(hsh[1][k], wv, a1);
            a2 = fmaf(hsh[2][k], wv, a2);
            a3 = fmaf(hsh[3][k], wv, a3);
        }
        dsh[0][tid] = a0; dsh[1][tid] = a1; dsh[2][tid] = a2; dsh[3][tid] = a3;
    }
    __syncthreads();

    if (tid < OD) {
        float mu[4], sg[4];
        #pragma unroll
        for (int rr = 0; rr < 4; ++rr) { mu[rr] = bmu[tid]; sg[rr] = bsg[tid]; }
        for (int i = 0; i < DN; ++i) {
            const float wm = Wmu[i * OD + tid];
            const float ws = Wsg[i * OD + tid];
            #pragma unroll
            for (int rr = 0; rr < 4; ++rr) {
                const float dv = dsh[rr][i];
                mu[rr] = fmaf(dv, wm, mu[rr]);
                sg[rr] = fmaf(dv, ws, sg[rr]);
            }
        }
        #pragma unroll
        for (int rr = 0; rr < 4; ++rr) {
            const float s = sg[rr];
            const float sp = (s > 20.f) ? s : log1pf(expf(s));
            const size_t oi = (size_t)b * (WW * OD) + (size_t)(t0 + rr) * OD + tid;
            out[oi] = mu[rr] + sp * noise[oi];
        }
    }
}

extern "C" void kernel_launch(void* const* d_in, const int* in_sizes, int n_in,
                              void* d_out, int out_size, void* d_ws, size_t ws_size,
                              hipStream_t stream)
{
    const float* z     = (const float*)d_in[0];
    const float* noise = (const float*)d_in[1];
    const float* W_L   = (const float*)d_in[2];
    const float* b_L   = (const float*)d_in[3];
    const float* W_ih  = (const float*)d_in[4];
    const float* b_ih  = (const float*)d_in[5];
    const float* W_hh  = (const float*)d_in[6];
    const float* b_hh  = (const float*)d_in[7];
    const float* W_d   = (const float*)d_in[8];
    const float* b_d   = (const float*)d_in[9];
    const float* W_mu  = (const float*)d_in[10];
    const float* b_mu  = (const float*)d_in[11];
    const float* W_sg  = (const float*)d_in[12];
    const float* b_sg  = (const float*)d_in[13];
    float* out = (float*)d_out;

    float* X    = (float*)d_ws;                     // 4096*4096
    float* GIb  = X + (size_t)ROWS * ZD;            // 4096*3072
    float* Hall = GIb + (size_t)ROWS * G3;          // 512*8*1024

    // X = Z @ W_lgssm + b_lgssm
    gemm_f32<<<dim3(ZD / BN, ROWS / BM), 256, 0, stream>>>(z, W_L, b_L, X, ROWS, ZD, ZD);
    // GI = X @ W_ih + b_ih
    gemm_f32<<<dim3(G3 / BN, ROWS / BM), 256, 0, stream>>>(X, W_ih, b_ih, GIb, ROWS, G3, ZD);

    // sequential GRU scan (cooperative, grid-wide barrier per timestep)
    void* args[] = { (void*)&GIb, (void*)&W_hh, (void*)&b_hh, (void*)&Hall };
    hipLaunchCooperativeKernel((void*)recur_kernel, dim3(HID / 4), dim3(256), args, 0, stream);

    // dense + mu/sigma heads + sample
    head_kernel<<<dim3(ROWS / 4), 128, 0, stream>>>(Hall, W_d, b_d, W_mu, b_mu, W_sg, b_sg, noise, out);
}

// Round 2
// 15800.664 us; speedup vs baseline: 1.2300x; 1.2300x over previous
//
#include <hip/hip_runtime.h>
#include <cmath>

#define ZD    4096
#define HID   1024
#define G3    3072
#define DN    100
#define OD    100
#define BB    8
#define WW    512
#define ROWS  4096   // B*W

// ---------------- fp32 GEMM: C[M,N] = A[M,K] @ B[K,N] + bias[N] ----------------
#define BM 64
#define BN 128
#define BK 16

__global__ __launch_bounds__(256) void gemm_f32(
    const float* __restrict__ A, const float* __restrict__ B,
    const float* __restrict__ bias, float* __restrict__ C,
    int M, int N, int K)
{
    __shared__ __align__(16) float As[BK][BM + 4];
    __shared__ __align__(16) float Bs[BK][BN + 4];
    const int tid = threadIdx.x;
    const int tx = tid & 15;        // -> m (4 rows)
    const int ty = tid >> 4;        // -> n (8 cols)
    const int bm0 = blockIdx.y * BM;
    const int bn0 = blockIdx.x * BN;

    float acc[4][8] = {};

    for (int k0 = 0; k0 < K; k0 += BK) {
        // A tile 64x16, store transposed
        {
            const int mr = tid >> 2;
            const int kc = (tid & 3) << 2;
            float4 av = *(const float4*)(A + (size_t)(bm0 + mr) * K + k0 + kc);
            As[kc + 0][mr] = av.x;
            As[kc + 1][mr] = av.y;
            As[kc + 2][mr] = av.z;
            As[kc + 3][mr] = av.w;
        }
        // B tile 16x128: 512 float4, 2 per thread
        #pragma unroll
        for (int i = 0; i < 2; ++i) {
            const int v = tid + (i << 8);
            const int kr = v >> 5;
            const int nc = (v & 31) << 2;
            *(float4*)&Bs[kr][nc] =
                *(const float4*)(B + (size_t)(k0 + kr) * N + bn0 + nc);
        }
        __syncthreads();
        #pragma unroll
        for (int kk = 0; kk < BK; ++kk) {
            float4 a  = *(const float4*)&As[kk][tx << 2];
            float4 b0 = *(const float4*)&Bs[kk][ty << 3];
            float4 b1 = *(const float4*)&Bs[kk][(ty << 3) + 4];
            const float av[4] = {a.x, a.y, a.z, a.w};
            const float bv[8] = {b0.x, b0.y, b0.z, b0.w, b1.x, b1.y, b1.z, b1.w};
            #pragma unroll
            for (int i = 0; i < 4; ++i)
                #pragma unroll
                for (int j = 0; j < 8; ++j)
                    acc[i][j] = fmaf(av[i], bv[j], acc[i][j]);
        }
        __syncthreads();
    }

    #pragma unroll
    for (int i = 0; i < 4; ++i) {
        const int row = bm0 + (tx << 2) + i;
        float* crow = C + (size_t)row * N + bn0 + (ty << 3);
        const float* brow = bias + bn0 + (ty << 3);
        float4 o0 = make_float4(acc[i][0] + brow[0], acc[i][1] + brow[1],
                                acc[i][2] + brow[2], acc[i][3] + brow[3]);
        float4 o1 = make_float4(acc[i][4] + brow[4], acc[i][5] + brow[5],
                                acc[i][6] + brow[6], acc[i][7] + brow[7]);
        *(float4*)crow = o0;
        *(float4*)(crow + 4) = o1;
    }
}

// ---------------- persistent GRU recurrence with fast custom barrier ----------------
// 256 blocks x 256 threads (cooperative launch for co-residency guarantee only).
// Wave wv of block g owns hidden unit nh = g*4+wv; its 3 gate columns of W_hh
// are register-resident (48 floats/lane, lane owns k = j*256 + lane*4 + q).
// Hm has WW+1 slots of (BB*HID); slot 0 is zeroed (h_{-1} = 0), slot t+1 = h_t.
__global__ __launch_bounds__(256) void recur_kernel(
    const float* __restrict__ GI, const float* __restrict__ Whh,
    const float* __restrict__ bhh, float* __restrict__ Hm,
    unsigned* __restrict__ bar)
{
    __shared__ __align__(16) float hs[BB][HID];
    const int tid = threadIdx.x;
    const int lane = tid & 63;
    const int wv = tid >> 6;
    const int nh = blockIdx.x * 4 + wv;

    float wr0[16], wr1[16], wr2[16];
    #pragma unroll
    for (int j = 0; j < 4; ++j)
        #pragma unroll
        for (int q = 0; q < 4; ++q) {
            const int k = (j << 8) + (lane << 2) + q;
            const float* wrow = Whh + (size_t)k * G3;
            wr0[(j << 2) + q] = wrow[nh];
            wr1[(j << 2) + q] = wrow[HID + nh];
            wr2[(j << 2) + q] = wrow[2 * HID + nh];
        }
    const float bh0 = bhh[nh];
    const float bh1 = bhh[HID + nh];
    const float bh2 = bhh[2 * HID + nh];

    for (int t = 0; t < WW; ++t) {
        // gi prefetch for this wave's unit, lanes 0..7 = batch index (h-independent)
        float gi_r = 0.f, gi_u = 0.f, gi_n = 0.f;
        if (lane < 8) {
            const float* gp = GI + ((size_t)lane * WW + t) * G3;
            gi_r = gp[nh];
            gi_u = gp[HID + nh];
            gi_n = gp[2 * HID + nh];
        }
        // stage h_{t-1} (slot t) into LDS: one 32KB read per block
        {
            const float4* hp = (const float4*)(Hm + (size_t)t * (BB * HID));
            float4* hd = (float4*)hs;
            #pragma unroll
            for (int i = 0; i < 8; ++i) hd[tid + (i << 8)] = hp[tid + (i << 8)];
        }
        __syncthreads();

        float s0 = 0.f, s1 = 0.f, s2 = 0.f;
        #pragma unroll
        for (int b = 0; b < BB; ++b) {
            const float4* hb = (const float4*)&hs[b][0];
            float p0 = 0.f, p1 = 0.f, p2 = 0.f;
            #pragma unroll
            for (int j = 0; j < 4; ++j) {
                float4 h4 = hb[(j << 6) + lane];
                const float hv[4] = {h4.x, h4.y, h4.z, h4.w};
                #pragma unroll
                for (int q = 0; q < 4; ++q) {
                    p0 = fmaf(hv[q], wr0[(j << 2) + q], p0);
                    p1 = fmaf(hv[q], wr1[(j << 2) + q], p1);
                    p2 = fmaf(hv[q], wr2[(j << 2) + q], p2);
                }
            }
            #pragma unroll
            for (int m = 32; m >= 1; m >>= 1) {
                p0 += __shfl_xor(p0, m, 64);
                p1 += __shfl_xor(p1, m, 64);
                p2 += __shfl_xor(p2, m, 64);
            }
            // every lane now has the full sums for batch b; lane b keeps them
            if (lane == b) { s0 = p0; s1 = p1; s2 = p2; }
        }
        // lanes 0..7 apply the GRU update for (batch=lane, unit=nh)
        if (lane < 8) {
            const float hold = hs[lane][nh];
            const float ghr = s0 + bh0;
            const float ghu = s1 + bh1;
            const float ghn = s2 + bh2;
            const float r = 1.f / (1.f + expf(-(gi_r + ghr)));
            const float u = 1.f / (1.f + expf(-(gi_u + ghu)));
            const float n = tanhf(gi_n + r * ghn);
            const float hnew = (1.f - u) * n + u * hold;
            Hm[(size_t)(t + 1) * (BB * HID) + lane * HID + nh] = hnew;
        }
        __syncthreads();   // drain stores (vmcnt) + protect hs before restage

        if (t < WW - 1) {
            if (tid == 0) {
                __threadfence();  // release: write back this XCD's L2 to common point
                __hip_atomic_fetch_add(bar, 1u, __ATOMIC_RELEASE, __HIP_MEMORY_SCOPE_AGENT);
                const unsigned tgt = 256u * (unsigned)(t + 1);
                while (__hip_atomic_load(bar, __ATOMIC_RELAXED, __HIP_MEMORY_SCOPE_AGENT) < tgt) {}
                __threadfence();  // acquire: invalidate stale L1/L2 before h reads
            }
            __syncthreads();
        }
    }
}

// ---------------- dense + heads + reparameterized sample ----------------
// 1024 blocks x 128 threads; each block does 4 consecutive timesteps of one batch.
__global__ __launch_bounds__(128) void head_kernel(
    const float* __restrict__ Hall, const float* __restrict__ Wd,
    const float* __restrict__ bd, const float* __restrict__ Wmu,
    const float* __restrict__ bmu, const float* __restrict__ Wsg,
    const float* __restrict__ bsg, const float* __restrict__ noise,
    float* __restrict__ out)
{
    const int blk = blockIdx.x;        // 0..1023
    const int b = blk >> 7;            // batch
    const int t0 = (blk & 127) << 2;   // 4 timesteps
    __shared__ __align__(16) float hsh[4][HID];
    __shared__ float dsh[4][DN];
    const int tid = threadIdx.x;

    #pragma unroll
    for (int rr = 0; rr < 4; ++rr) {
        const float4* hp = (const float4*)(Hall + (size_t)(t0 + rr) * (BB * HID) + (size_t)b * HID);
        ((float4*)hsh[rr])[tid] = hp[tid];
        ((float4*)hsh[rr])[tid + 128] = hp[tid + 128];
    }
    __syncthreads();

    if (tid < DN) {
        float a0 = bd[tid], a1 = bd[tid], a2 = bd[tid], a3 = bd[tid];
        for (int k = 0; k < HID; ++k) {
            const float wv = Wd[k * DN + tid];
            a0 = fmaf(hsh[0][k], wv, a0);
            a1 = fmaf(hsh[1][k], wv, a1);
            a2 = fmaf(hsh[2][k], wv, a2);
            a3 = fmaf(hsh[3][k], wv, a3);
        }
        dsh[0][tid] = a0; dsh[1][tid] = a1; dsh[2][tid] = a2; dsh[3][tid] = a3;
    }
    __syncthreads();

    if (tid < OD) {
        float mu[4], sg[4];
        #pragma unroll
        for (int rr = 0; rr < 4; ++rr) { mu[rr] = bmu[tid]; sg[rr] = bsg[tid]; }
        for (int i = 0; i < DN; ++i) {
            const float wm = Wmu[i * OD + tid];
            const float ws = Wsg[i * OD + tid];
            #pragma unroll
            for (int rr = 0; rr < 4; ++rr) {
                const float dv = dsh[rr][i];
                mu[rr] = fmaf(dv, wm, mu[rr]);
                sg[rr] = fmaf(dv, ws, sg[rr]);
            }
        }
        #pragma unroll
        for (int rr = 0; rr < 4; ++rr) {
            const float s = sg[rr];
            const float sp = (s > 20.f) ? s : log1pf(expf(s));
            const size_t oi = (size_t)b * (WW * OD) + (size_t)(t0 + rr) * OD + tid;
            out[oi] = mu[rr] + sp * noise[oi];
        }
    }
}

extern "C" void kernel_launch(void* const* d_in, const int* in_sizes, int n_in,
                              void* d_out, int out_size, void* d_ws, size_t ws_size,
                              hipStream_t stream)
{
    const float* z     = (const float*)d_in[0];
    const float* noise = (const float*)d_in[1];
    const float* W_L   = (const float*)d_in[2];
    const float* b_L   = (const float*)d_in[3];
    const float* W_ih  = (const float*)d_in[4];
    const float* b_ih  = (const float*)d_in[5];
    const float* W_hh  = (const float*)d_in[6];
    const float* b_hh  = (const float*)d_in[7];
    const float* W_d   = (const float*)d_in[8];
    const float* b_d   = (const float*)d_in[9];
    const float* W_mu  = (const float*)d_in[10];
    const float* b_mu  = (const float*)d_in[11];
    const float* W_sg  = (const float*)d_in[12];
    const float* b_sg  = (const float*)d_in[13];
    float* out = (float*)d_out;

    float* X    = (float*)d_ws;                      // 4096*4096
    float* GIb  = X + (size_t)ROWS * ZD;             // 4096*3072
    float* Hm   = GIb + (size_t)ROWS * G3;           // (512+1)*8192, slot 0 = h_{-1}=0
    unsigned* bar = (unsigned*)(Hm + (size_t)(WW + 1) * (BB * HID));

    // zero h_{-1} slot and the barrier counter (d_ws is poisoned before every launch)
    hipMemsetAsync(Hm, 0, (size_t)(BB * HID) * sizeof(float), stream);
    hipMemsetAsync(bar, 0, 256, stream);

    // X = Z @ W_lgssm + b_lgssm
    gemm_f32<<<dim3(ZD / BN, ROWS / BM), 256, 0, stream>>>(z, W_L, b_L, X, ROWS, ZD, ZD);
    // GI = X @ W_ih + b_ih
    gemm_f32<<<dim3(G3 / BN, ROWS / BM), 256, 0, stream>>>(X, W_ih, b_ih, GIb, ROWS, G3, ZD);

    // sequential GRU scan (custom device-scope barrier per timestep;
    // cooperative launch used only to guarantee co-residency of all 256 blocks)
    void* args[] = { (void*)&GIb, (void*)&W_hh, (void*)&b_hh, (void*)&Hm, (void*)&bar };
    hipLaunchCooperativeKernel((void*)recur_kernel, dim3(HID / 4), dim3(256), args, 0, stream);

    // dense + mu/sigma heads + sample (h_t lives in Hm slot t+1)
    head_kernel<<<dim3(ROWS / 4), 128, 0, stream>>>(Hm + BB * HID, W_d, b_d, W_mu, b_mu, W_sg, b_sg, noise, out);
}

// Round 3
// 11250.188 us; speedup vs baseline: 1.7276x; 1.4045x over previous
//
#include <hip/hip_runtime.h>
#include <cmath>

#define ZD    4096
#define HID   1024
#define G3    3072
#define DN    100
#define OD    100
#define BB    8
#define WW    512
#define ROWS  4096   // B*W

// Relaxed agent-scope (device-coherent) accessors: compile to global_load/store
// with sc0 sc1 -> bypass L1/L2, served by L3. No wbl2/inv cache sweeps needed.
__device__ __forceinline__ float load_dc(const float* p) {
    return __hip_atomic_load(p, __ATOMIC_RELAXED, __HIP_MEMORY_SCOPE_AGENT);
}
__device__ __forceinline__ void store_dc(float* p, float v) {
    __hip_atomic_store(p, v, __ATOMIC_RELAXED, __HIP_MEMORY_SCOPE_AGENT);
}

// ---------------- fp32 GEMM: C[M,N] = A[M,K] @ B[K,N] + bias[N] ----------------
#define BM 64
#define BN 128
#define BK 16

__global__ __launch_bounds__(256) void gemm_f32(
    const float* __restrict__ A, const float* __restrict__ B,
    const float* __restrict__ bias, float* __restrict__ C,
    int M, int N, int K)
{
    __shared__ __align__(16) float As[BK][BM + 4];
    __shared__ __align__(16) float Bs[BK][BN + 4];
    const int tid = threadIdx.x;
    const int tx = tid & 15;        // -> m (4 rows)
    const int ty = tid >> 4;        // -> n (8 cols)
    const int bm0 = blockIdx.y * BM;
    const int bn0 = blockIdx.x * BN;

    float acc[4][8] = {};

    for (int k0 = 0; k0 < K; k0 += BK) {
        {
            const int mr = tid >> 2;
            const int kc = (tid & 3) << 2;
            float4 av = *(const float4*)(A + (size_t)(bm0 + mr) * K + k0 + kc);
            As[kc + 0][mr] = av.x;
            As[kc + 1][mr] = av.y;
            As[kc + 2][mr] = av.z;
            As[kc + 3][mr] = av.w;
        }
        #pragma unroll
        for (int i = 0; i < 2; ++i) {
            const int v = tid + (i << 8);
            const int kr = v >> 5;
            const int nc = (v & 31) << 2;
            *(float4*)&Bs[kr][nc] =
                *(const float4*)(B + (size_t)(k0 + kr) * N + bn0 + nc);
        }
        __syncthreads();
        #pragma unroll
        for (int kk = 0; kk < BK; ++kk) {
            float4 a  = *(const float4*)&As[kk][tx << 2];
            float4 b0 = *(const float4*)&Bs[kk][ty << 3];
            float4 b1 = *(const float4*)&Bs[kk][(ty << 3) + 4];
            const float av[4] = {a.x, a.y, a.z, a.w};
            const float bv[8] = {b0.x, b0.y, b0.z, b0.w, b1.x, b1.y, b1.z, b1.w};
            #pragma unroll
            for (int i = 0; i < 4; ++i)
                #pragma unroll
                for (int j = 0; j < 8; ++j)
                    acc[i][j] = fmaf(av[i], bv[j], acc[i][j]);
        }
        __syncthreads();
    }

    #pragma unroll
    for (int i = 0; i < 4; ++i) {
        const int row = bm0 + (tx << 2) + i;
        float* crow = C + (size_t)row * N + bn0 + (ty << 3);
        const float* brow = bias + bn0 + (ty << 3);
        float4 o0 = make_float4(acc[i][0] + brow[0], acc[i][1] + brow[1],
                                acc[i][2] + brow[2], acc[i][3] + brow[3]);
        float4 o1 = make_float4(acc[i][4] + brow[4], acc[i][5] + brow[5],
                                acc[i][6] + brow[6], acc[i][7] + brow[7]);
        *(float4*)crow = o0;
        *(float4*)(crow + 4) = o1;
    }
}

// ---------------- persistent GRU recurrence, fence-free L3 barrier ----------------
// 256 blocks x 256 threads. Wave wv of block g owns hidden unit nh = g*4+wv;
// its 3 gate columns of W_hh are register-resident (48 floats/lane).
// All cross-block data (h, counters) moves via relaxed agent-scope atomics
// (sc0 sc1 -> L3 direct), so no buffer_wbl2/buffer_inv sweeps are ever emitted.
// Hm has WW+1 slots of (BB*HID); slot 0 zeroed (h_{-1}=0), slot t+1 = h_t.
// Barrier: 32 leaf counters (one 128B line each, 8 blocks/leaf) + 1 root.
__global__ __launch_bounds__(256) void recur_kernel(
    const float* __restrict__ GI, const float* __restrict__ Whh,
    const float* __restrict__ bhh, float* __restrict__ Hm,
    unsigned* __restrict__ bar)
{
    __shared__ __align__(16) float hs[BB][HID];
    const int tid = threadIdx.x;
    const int lane = tid & 63;
    const int wv = tid >> 6;
    const int nh = blockIdx.x * 4 + wv;
    unsigned* leaf = bar + ((blockIdx.x & 31) << 5);  // 128B-spaced leaf lines
    unsigned* root = bar + 1024;                      // own line

    float wr0[16], wr1[16], wr2[16];
    #pragma unroll
    for (int j = 0; j < 4; ++j)
        #pragma unroll
        for (int q = 0; q < 4; ++q) {
            const int k = (j << 8) + (lane << 2) + q;
            const float* wrow = Whh + (size_t)k * G3;
            wr0[(j << 2) + q] = wrow[nh];
            wr1[(j << 2) + q] = wrow[HID + nh];
            wr2[(j << 2) + q] = wrow[2 * HID + nh];
        }
    const float bh0 = bhh[nh];
    const float bh1 = bhh[HID + nh];
    const float bh2 = bhh[2 * HID + nh];

    for (int t = 0; t < WW; ++t) {
        // gi prefetch (h-independent), lanes 0..7 = batch index
        float gi_r = 0.f, gi_u = 0.f, gi_n = 0.f;
        if (lane < 8) {
            const float* gp = GI + ((size_t)lane * WW + t) * G3;
            gi_r = gp[nh];
            gi_u = gp[HID + nh];
            gi_n = gp[2 * HID + nh];
        }
        // stage h_{t-1} (slot t) into LDS via device-coherent loads (from L3)
        {
            const float* hp = Hm + (size_t)t * (BB * HID);
            float* hd = (float*)hs;
            #pragma unroll
            for (int i = 0; i < 32; ++i)
                hd[tid + (i << 8)] = load_dc(hp + tid + (i << 8));
        }
        __syncthreads();

        float s0 = 0.f, s1 = 0.f, s2 = 0.f;
        #pragma unroll
        for (int b = 0; b < BB; ++b) {
            const float4* hb = (const float4*)&hs[b][0];
            float p0 = 0.f, p1 = 0.f, p2 = 0.f;
            #pragma unroll
            for (int j = 0; j < 4; ++j) {
                float4 h4 = hb[(j << 6) + lane];
                const float hv[4] = {h4.x, h4.y, h4.z, h4.w};
                #pragma unroll
                for (int q = 0; q < 4; ++q) {
                    p0 = fmaf(hv[q], wr0[(j << 2) + q], p0);
                    p1 = fmaf(hv[q], wr1[(j << 2) + q], p1);
                    p2 = fmaf(hv[q], wr2[(j << 2) + q], p2);
                }
            }
            #pragma unroll
            for (int m = 32; m >= 1; m >>= 1) {
                p0 += __shfl_xor(p0, m, 64);
                p1 += __shfl_xor(p1, m, 64);
                p2 += __shfl_xor(p2, m, 64);
            }
            if (lane == b) { s0 = p0; s1 = p1; s2 = p2; }
        }
        // lanes 0..7 apply GRU update for (batch=lane, unit=nh), write through to L3
        if (lane < 8) {
            const float hold = hs[lane][nh];
            const float r = 1.f / (1.f + expf(-(gi_r + s0 + bh0)));
            const float u = 1.f / (1.f + expf(-(gi_u + s1 + bh1)));
            const float n = tanhf(gi_n + r * (s2 + bh2));
            const float hnew = (1.f - u) * n + u * hold;
            store_dc(Hm + (size_t)(t + 1) * (BB * HID) + lane * HID + nh, hnew);
        }
        __syncthreads();   // s_waitcnt vmcnt(0): all block's h stores are at L3

        if (t < WW - 1) {
            if (tid == 0) {
                // two-level arrival: 8 arrivals/leaf, last-of-8 bumps root
                unsigned a = __hip_atomic_fetch_add(leaf, 1u, __ATOMIC_RELAXED,
                                                    __HIP_MEMORY_SCOPE_AGENT);
                if ((a & 7u) == 7u)
                    __hip_atomic_fetch_add(root, 1u, __ATOMIC_RELAXED,
                                           __HIP_MEMORY_SCOPE_AGENT);
                const unsigned tgt = 32u * (unsigned)(t + 1);
                while (__hip_atomic_load(root, __ATOMIC_RELAXED,
                                         __HIP_MEMORY_SCOPE_AGENT) < tgt)
                    __builtin_amdgcn_s_sleep(1);
            }
            __syncthreads();
        }
    }
}

// ---------------- dense + heads + reparameterized sample ----------------
__global__ __launch_bounds__(128) void head_kernel(
    const float* __restrict__ Hall, const float* __restrict__ Wd,
    const float* __restrict__ bd, const float* __restrict__ Wmu,
    const float* __restrict__ bmu, const float* __restrict__ Wsg,
    const float* __restrict__ bsg, const float* __restrict__ noise,
    float* __restrict__ out)
{
    const int blk = blockIdx.x;        // 0..1023
    const int b = blk >> 7;            // batch
    const int t0 = (blk & 127) << 2;   // 4 timesteps
    __shared__ __align__(16) float hsh[4][HID];
    __shared__ float dsh[4][DN];
    const int tid = threadIdx.x;

    #pragma unroll
    for (int rr = 0; rr < 4; ++rr) {
        const float4* hp = (const float4*)(Hall + (size_t)(t0 + rr) * (BB * HID) + (size_t)b * HID);
        ((float4*)hsh[rr])[tid] = hp[tid];
        ((float4*)hsh[rr])[tid + 128] = hp[tid + 128];
    }
    __syncthreads();

    if (tid < DN) {
        float a0 = bd[tid], a1 = bd[tid], a2 = bd[tid], a3 = bd[tid];
        for (int k = 0; k < HID; ++k) {
            const float wv = Wd[k * DN + tid];
            a0 = fmaf(hsh[0][k], wv, a0);
            a1 = fmaf(hsh[1][k], wv, a1);
            a2 = fmaf(hsh[2][k], wv, a2);
            a3 = fmaf(hsh[3][k], wv, a3);
        }
        dsh[0][tid] = a0; dsh[1][tid] = a1; dsh[2][tid] = a2; dsh[3][tid] = a3;
    }
    __syncthreads();

    if (tid < OD) {
        float mu[4], sg[4];
        #pragma unroll
        for (int rr = 0; rr < 4; ++rr) { mu[rr] = bmu[tid]; sg[rr] = bsg[tid]; }
        for (int i = 0; i < DN; ++i) {
            const float wm = Wmu[i * OD + tid];
            const float ws = Wsg[i * OD + tid];
            #pragma unroll
            for (int rr = 0; rr < 4; ++rr) {
                const float dv = dsh[rr][i];
                mu[rr] = fmaf(dv, wm, mu[rr]);
                sg[rr] = fmaf(dv, ws, sg[rr]);
            }
        }
        #pragma unroll
        for (int rr = 0; rr < 4; ++rr) {
            const float s = sg[rr];
            const float sp = (s > 20.f) ? s : log1pf(expf(s));
            const size_t oi = (size_t)b * (WW * OD) + (size_t)(t0 + rr) * OD + tid;
            out[oi] = mu[rr] + sp * noise[oi];
        }
    }
}

extern "C" void kernel_launch(void* const* d_in, const int* in_sizes, int n_in,
                              void* d_out, int out_size, void* d_ws, size_t ws_size,
                              hipStream_t stream)
{
    const float* z     = (const float*)d_in[0];
    const float* noise = (const float*)d_in[1];
    const float* W_L   = (const float*)d_in[2];
    const float* b_L   = (const float*)d_in[3];
    const float* W_ih  = (const float*)d_in[4];
    const float* b_ih  = (const float*)d_in[5];
    const float* W_hh  = (const float*)d_in[6];
    const float* b_hh  = (const float*)d_in[7];
    const float* W_d   = (const float*)d_in[8];
    const float* b_d   = (const float*)d_in[9];
    const float* W_mu  = (const float*)d_in[10];
    const float* b_mu  = (const float*)d_in[11];
    const float* W_sg  = (const float*)d_in[12];
    const float* b_sg  = (const float*)d_in[13];
    float* out = (float*)d_out;

    float* X    = (float*)d_ws;                      // 4096*4096
    float* GIb  = X + (size_t)ROWS * ZD;             // 4096*3072
    float* Hm   = GIb + (size_t)ROWS * G3;           // (512+1)*8192, slot 0 = h_{-1}=0
    unsigned* bar = (unsigned*)(Hm + (size_t)(WW + 1) * (BB * HID));  // 32 leaves + root

    // zero h_{-1} slot and barrier counters (d_ws is re-poisoned before every launch)
    hipMemsetAsync(Hm, 0, (size_t)(BB * HID) * sizeof(float), stream);
    hipMemsetAsync(bar, 0, 8192, stream);

    // X = Z @ W_lgssm + b_lgssm
    gemm_f32<<<dim3(ZD / BN, ROWS / BM), 256, 0, stream>>>(z, W_L, b_L, X, ROWS, ZD, ZD);
    // GI = X @ W_ih + b_ih
    gemm_f32<<<dim3(G3 / BN, ROWS / BM), 256, 0, stream>>>(X, W_ih, b_ih, GIb, ROWS, G3, ZD);

    // sequential GRU scan (fence-free L3 barrier; cooperative launch only for
    // the co-residency guarantee)
    void* args[] = { (void*)&GIb, (void*)&W_hh, (void*)&b_hh, (void*)&Hm, (void*)&bar };
    hipLaunchCooperativeKernel((void*)recur_kernel, dim3(HID / 4), dim3(256), args, 0, stream);

    // dense + mu/sigma heads + sample (h_t lives in Hm slot t+1)
    head_kernel<<<dim3(ROWS / 4), 128, 0, stream>>>(Hm + BB * HID, W_d, b_d, W_mu, b_mu, W_sg, b_sg, noise, out);
}

// Round 4
// 9879.210 us; speedup vs baseline: 1.9673x; 1.1388x over previous
//
#include <hip/hip_runtime.h>
#include <cmath>

#define ZD    4096
#define HID   1024
#define G3    3072
#define DN    100
#define OD    100
#define BB    8
#define WW    512
#define ROWS  4096   // B*W

// Relaxed agent-scope (device-coherent) accessors: compile to global_load/store
// with sc0 sc1 -> bypass L1/L2, served by L3. No wbl2/inv cache sweeps needed.
__device__ __forceinline__ float load_dc(const float* p) {
    return __hip_atomic_load(p, __ATOMIC_RELAXED, __HIP_MEMORY_SCOPE_AGENT);
}
__device__ __forceinline__ void store_dc(float* p, float v) {
    __hip_atomic_store(p, v, __ATOMIC_RELAXED, __HIP_MEMORY_SCOPE_AGENT);
}

// ---------------- fp32 GEMM: C[M,N] = A[M,K] @ B[K,N] + bias[N] ----------------
#define BM 64
#define BN 128
#define BK 16

__global__ __launch_bounds__(256) void gemm_f32(
    const float* __restrict__ A, const float* __restrict__ B,
    const float* __restrict__ bias, float* __restrict__ C,
    int M, int N, int K)
{
    __shared__ __align__(16) float As[BK][BM + 4];
    __shared__ __align__(16) float Bs[BK][BN + 4];
    const int tid = threadIdx.x;
    const int tx = tid & 15;        // -> m (4 rows)
    const int ty = tid >> 4;        // -> n (8 cols)
    const int bm0 = blockIdx.y * BM;
    const int bn0 = blockIdx.x * BN;

    float acc[4][8] = {};

    for (int k0 = 0; k0 < K; k0 += BK) {
        {
            const int mr = tid >> 2;
            const int kc = (tid & 3) << 2;
            float4 av = *(const float4*)(A + (size_t)(bm0 + mr) * K + k0 + kc);
            As[kc + 0][mr] = av.x;
            As[kc + 1][mr] = av.y;
            As[kc + 2][mr] = av.z;
            As[kc + 3][mr] = av.w;
        }
        #pragma unroll
        for (int i = 0; i < 2; ++i) {
            const int v = tid + (i << 8);
            const int kr = v >> 5;
            const int nc = (v & 31) << 2;
            *(float4*)&Bs[kr][nc] =
                *(const float4*)(B + (size_t)(k0 + kr) * N + bn0 + nc);
        }
        __syncthreads();
        #pragma unroll
        for (int kk = 0; kk < BK; ++kk) {
            float4 a  = *(const float4*)&As[kk][tx << 2];
            float4 b0 = *(const float4*)&Bs[kk][ty << 3];
            float4 b1 = *(const float4*)&Bs[kk][(ty << 3) + 4];
            const float av[4] = {a.x, a.y, a.z, a.w};
            const float bv[8] = {b0.x, b0.y, b0.z, b0.w, b1.x, b1.y, b1.z, b1.w};
            #pragma unroll
            for (int i = 0; i < 4; ++i)
                #pragma unroll
                for (int j = 0; j < 8; ++j)
                    acc[i][j] = fmaf(av[i], bv[j], acc[i][j]);
        }
        __syncthreads();
    }

    #pragma unroll
    for (int i = 0; i < 4; ++i) {
        const int row = bm0 + (tx << 2) + i;
        float* crow = C + (size_t)row * N + bn0 + (ty << 3);
        const float* brow = bias + bn0 + (ty << 3);
        float4 o0 = make_float4(acc[i][0] + brow[0], acc[i][1] + brow[1],
                                acc[i][2] + brow[2], acc[i][3] + brow[3]);
        float4 o1 = make_float4(acc[i][4] + brow[4], acc[i][5] + brow[5],
                                acc[i][6] + brow[6], acc[i][7] + brow[7]);
        *(float4*)crow = o0;
        *(float4*)(crow + 4) = o1;
    }
}

// ---------------- persistent GRU recurrence, broadcast-release L3 barrier ----------------
// 256 blocks x 256 threads. Wave wv of block g owns hidden unit nh = g*4+wv;
// its 3 gate columns of W_hh are register-resident (48 floats/lane).
// Cross-block data (h, counters) moves via relaxed agent-scope atomics (L3 direct).
// Barrier: 32 leaf arrival counters (8 blocks each) -> 1 root; the globally-last
// block broadcasts the epoch to 32 release lines; each block polls ONLY its own
// release line (8 pollers/line) -- avoids the 256-poller hot-line queue at L3.
// Hm has WW+1 slots of (BB*HID); slot 0 zeroed (h_{-1}=0), slot t+1 = h_t.
__global__ __launch_bounds__(256) void recur_kernel(
    const float* __restrict__ GI, const float* __restrict__ Whh,
    const float* __restrict__ bhh, float* __restrict__ Hm,
    unsigned* __restrict__ bar)
{
    __shared__ __align__(16) float hs[BB][HID];
    const int tid = threadIdx.x;
    const int lane = tid & 63;
    const int wv = tid >> 6;
    const int nh = blockIdx.x * 4 + wv;
    const int leaf_i = blockIdx.x & 31;
    unsigned* leaf = bar + (leaf_i << 5);        // 128B-spaced leaf lines
    unsigned* root = bar + 1024;                 // own line
    unsigned* rel  = bar + 2048 + (leaf_i << 5); // 128B-spaced release lines

    float wr0[16], wr1[16], wr2[16];
    #pragma unroll
    for (int j = 0; j < 4; ++j)
        #pragma unroll
        for (int q = 0; q < 4; ++q) {
            const int k = (j << 8) + (lane << 2) + q;
            const float* wrow = Whh + (size_t)k * G3;
            wr0[(j << 2) + q] = wrow[nh];
            wr1[(j << 2) + q] = wrow[HID + nh];
            wr2[(j << 2) + q] = wrow[2 * HID + nh];
        }
    const float bh0 = bhh[nh];
    const float bh1 = bhh[HID + nh];
    const float bh2 = bhh[2 * HID + nh];

    // prefetch gi for t=0 (lanes 0..7 = batch index)
    float gi_r = 0.f, gi_u = 0.f, gi_n = 0.f;
    if (lane < 8) {
        const float* gp = GI + ((size_t)lane * WW + 0) * G3;
        gi_r = gp[nh];
        gi_u = gp[HID + nh];
        gi_n = gp[2 * HID + nh];
    }

    for (int t = 0; t < WW; ++t) {
        // stage h_{t-1} (slot t) into LDS via device-coherent loads (from L3)
        {
            const float* hp = Hm + (size_t)t * (BB * HID);
            float* hd = (float*)hs;
            #pragma unroll
            for (int i = 0; i < 32; ++i)
                hd[tid + (i << 8)] = load_dc(hp + tid + (i << 8));
        }
        // prefetch gi for t+1 (h-independent): hides HBM/L2 latency under this
        // step's compute + barrier instead of sitting on the critical path
        float gn_r = 0.f, gn_u = 0.f, gn_n = 0.f;
        if (lane < 8 && t + 1 < WW) {
            const float* gp = GI + ((size_t)lane * WW + (t + 1)) * G3;
            gn_r = gp[nh];
            gn_u = gp[HID + nh];
            gn_n = gp[2 * HID + nh];
        }
        __syncthreads();

        float s0 = 0.f, s1 = 0.f, s2 = 0.f;
        #pragma unroll
        for (int b = 0; b < BB; ++b) {
            const float4* hb = (const float4*)&hs[b][0];
            float p0 = 0.f, p1 = 0.f, p2 = 0.f;
            #pragma unroll
            for (int j = 0; j < 4; ++j) {
                float4 h4 = hb[(j << 6) + lane];
                const float hv[4] = {h4.x, h4.y, h4.z, h4.w};
                #pragma unroll
                for (int q = 0; q < 4; ++q) {
                    p0 = fmaf(hv[q], wr0[(j << 2) + q], p0);
                    p1 = fmaf(hv[q], wr1[(j << 2) + q], p1);
                    p2 = fmaf(hv[q], wr2[(j << 2) + q], p2);
                }
            }
            #pragma unroll
            for (int m = 32; m >= 1; m >>= 1) {
                p0 += __shfl_xor(p0, m, 64);
                p1 += __shfl_xor(p1, m, 64);
                p2 += __shfl_xor(p2, m, 64);
            }
            if (lane == b) { s0 = p0; s1 = p1; s2 = p2; }
        }
        // lanes 0..7 apply GRU update for (batch=lane, unit=nh), write through to L3
        if (lane < 8) {
            const float hold = hs[lane][nh];
            const float r = 1.f / (1.f + expf(-(gi_r + s0 + bh0)));
            const float u = 1.f / (1.f + expf(-(gi_u + s1 + bh1)));
            const float n = tanhf(gi_n + r * (s2 + bh2));
            const float hnew = (1.f - u) * n + u * hold;
            store_dc(Hm + (size_t)(t + 1) * (BB * HID) + lane * HID + nh, hnew);
        }
        __syncthreads();   // s_waitcnt vmcnt(0): all block's h stores are at L3

        if (t < WW - 1) {
            if (tid == 0) {
                // arrival tree: 8 arrivals/leaf; last-of-8 bumps root;
                // globally-last block broadcasts release epoch to all 32 lines
                unsigned a = __hip_atomic_fetch_add(leaf, 1u, __ATOMIC_RELAXED,
                                                    __HIP_MEMORY_SCOPE_AGENT);
                if ((a & 7u) == 7u) {
                    unsigned r = __hip_atomic_fetch_add(root, 1u, __ATOMIC_RELAXED,
                                                        __HIP_MEMORY_SCOPE_AGENT);
                    if (r == 32u * (unsigned)(t + 1) - 1u) {
                        #pragma unroll
                        for (int i = 0; i < 32; ++i)
                            __hip_atomic_store(bar + 2048 + (i << 5), (unsigned)(t + 1),
                                               __ATOMIC_RELAXED, __HIP_MEMORY_SCOPE_AGENT);
                    }
                }
                while (__hip_atomic_load(rel, __ATOMIC_RELAXED,
                                         __HIP_MEMORY_SCOPE_AGENT) < (unsigned)(t + 1))
                    __builtin_amdgcn_s_sleep(1);
            }
            __syncthreads();
        }
        gi_r = gn_r; gi_u = gn_u; gi_n = gn_n;
    }
}

// ---------------- dense + heads + reparameterized sample ----------------
__global__ __launch_bounds__(128) void head_kernel(
    const float* __restrict__ Hall, const float* __restrict__ Wd,
    const float* __restrict__ bd, const float* __restrict__ Wmu,
    const float* __restrict__ bmu, const float* __restrict__ Wsg,
    const float* __restrict__ bsg, const float* __restrict__ noise,
    float* __restrict__ out)
{
    const int blk = blockIdx.x;        // 0..1023
    const int b = blk >> 7;            // batch
    const int t0 = (blk & 127) << 2;   // 4 timesteps
    __shared__ __align__(16) float hsh[4][HID];
    __shared__ float dsh[4][DN];
    const int tid = threadIdx.x;

    #pragma unroll
    for (int rr = 0; rr < 4; ++rr) {
        const float4* hp = (const float4*)(Hall + (size_t)(t0 + rr) * (BB * HID) + (size_t)b * HID);
        ((float4*)hsh[rr])[tid] = hp[tid];
        ((float4*)hsh[rr])[tid + 128] = hp[tid + 128];
    }
    __syncthreads();

    if (tid < DN) {
        float a0 = bd[tid], a1 = bd[tid], a2 = bd[tid], a3 = bd[tid];
        for (int k = 0; k < HID; ++k) {
            const float wv = Wd[k * DN + tid];
            a0 = fmaf(hsh[0][k], wv, a0);
            a1 = fmaf(hsh[1][k], wv, a1);
            a2 = fmaf(hsh[2][k], wv, a2);
            a3 = fmaf(hsh[3][k], wv, a3);
        }
        dsh[0][tid] = a0; dsh[1][tid] = a1; dsh[2][tid] = a2; dsh[3][tid] = a3;
    }
    __syncthreads();

    if (tid < OD) {
        float mu[4], sg[4];
        #pragma unroll
        for (int rr = 0; rr < 4; ++rr) { mu[rr] = bmu[tid]; sg[rr] = bsg[tid]; }
        for (int i = 0; i < DN; ++i) {
            const float wm = Wmu[i * OD + tid];
            const float ws = Wsg[i * OD + tid];
            #pragma unroll
            for (int rr = 0; rr < 4; ++rr) {
                const float dv = dsh[rr][i];
                mu[rr] = fmaf(dv, wm, mu[rr]);
                sg[rr] = fmaf(dv, ws, sg[rr]);
            }
        }
        #pragma unroll
        for (int rr = 0; rr < 4; ++rr) {
            const float s = sg[rr];
            const float sp = (s > 20.f) ? s : log1pf(expf(s));
            const size_t oi = (size_t)b * (WW * OD) + (size_t)(t0 + rr) * OD + tid;
            out[oi] = mu[rr] + sp * noise[oi];
        }
    }
}

extern "C" void kernel_launch(void* const* d_in, const int* in_sizes, int n_in,
                              void* d_out, int out_size, void* d_ws, size_t ws_size,
                              hipStream_t stream)
{
    const float* z     = (const float*)d_in[0];
    const float* noise = (const float*)d_in[1];
    const float* W_L   = (const float*)d_in[2];
    const float* b_L   = (const float*)d_in[3];
    const float* W_ih  = (const float*)d_in[4];
    const float* b_ih  = (const float*)d_in[5];
    const float* W_hh  = (const float*)d_in[6];
    const float* b_hh  = (const float*)d_in[7];
    const float* W_d   = (const float*)d_in[8];
    const float* b_d   = (const float*)d_in[9];
    const float* W_mu  = (const float*)d_in[10];
    const float* b_mu  = (const float*)d_in[11];
    const float* W_sg  = (const float*)d_in[12];
    const float* b_sg  = (const float*)d_in[13];
    float* out = (float*)d_out;

    float* X    = (float*)d_ws;                      // 4096*4096
    float* GIb  = X + (size_t)ROWS * ZD;             // 4096*3072
    float* Hm   = GIb + (size_t)ROWS * G3;           // (512+1)*8192, slot 0 = h_{-1}=0
    unsigned* bar = (unsigned*)(Hm + (size_t)(WW + 1) * (BB * HID));  // leaves + root + release

    // zero h_{-1} slot and barrier/release lines (d_ws re-poisoned before every launch)
    hipMemsetAsync(Hm, 0, (size_t)(BB * HID) * sizeof(float), stream);
    hipMemsetAsync(bar, 0, 16384, stream);

    // X = Z @ W_lgssm + b_lgssm
    gemm_f32<<<dim3(ZD / BN, ROWS / BM), 256, 0, stream>>>(z, W_L, b_L, X, ROWS, ZD, ZD);
    // GI = X @ W_ih + b_ih
    gemm_f32<<<dim3(G3 / BN, ROWS / BM), 256, 0, stream>>>(X, W_ih, b_ih, GIb, ROWS, G3, ZD);

    // sequential GRU scan (broadcast-release L3 barrier; cooperative launch only
    // for the co-residency guarantee)
    void* args[] = { (void*)&GIb, (void*)&W_hh, (void*)&b_hh, (void*)&Hm, (void*)&bar };
    hipLaunchCooperativeKernel((void*)recur_kernel, dim3(HID / 4), dim3(256), args, 0, stream);

    // dense + mu/sigma heads + sample (h_t lives in Hm slot t+1)
    head_kernel<<<dim3(ROWS / 4), 128, 0, stream>>>(Hm + BB * HID, W_d, b_d, W_mu, b_mu, W_sg, b_sg, noise, out);
}

// Round 5
// 6204.312 us; speedup vs baseline: 3.1326x; 1.5923x over previous
//
#include <hip/hip_runtime.h>
#include <cmath>

#define ZD    4096
#define HID   1024
#define G3    3072
#define DN    100
#define OD    100
#define BB    8
#define WW    512
#define ROWS  4096   // B*W

// Relaxed agent-scope (device-coherent) accessors: compile to global_load/store
// with sc0 sc1 -> bypass L1/L2, served at the coherence point (L3).
__device__ __forceinline__ void store_dc(float* p, float v) {
    __hip_atomic_store(p, v, __ATOMIC_RELAXED, __HIP_MEMORY_SCOPE_AGENT);
}

// ---------------- fp32 GEMM: C[M,N] = A[M,K] @ B[K,N] + bias[N] ----------------
#define BM 64
#define BN 128
#define BK 16

__global__ __launch_bounds__(256) void gemm_f32(
    const float* __restrict__ A, const float* __restrict__ B,
    const float* __restrict__ bias, float* __restrict__ C,
    int M, int N, int K)
{
    __shared__ __align__(16) float As[BK][BM + 4];
    __shared__ __align__(16) float Bs[BK][BN + 4];
    const int tid = threadIdx.x;
    const int tx = tid & 15;        // -> m (4 rows)
    const int ty = tid >> 4;        // -> n (8 cols)
    const int bm0 = blockIdx.y * BM;
    const int bn0 = blockIdx.x * BN;

    float acc[4][8] = {};

    for (int k0 = 0; k0 < K; k0 += BK) {
        {
            const int mr = tid >> 2;
            const int kc = (tid & 3) << 2;
            float4 av = *(const float4*)(A + (size_t)(bm0 + mr) * K + k0 + kc);
            As[kc + 0][mr] = av.x;
            As[kc + 1][mr] = av.y;
            As[kc + 2][mr] = av.z;
            As[kc + 3][mr] = av.w;
        }
        #pragma unroll
        for (int i = 0; i < 2; ++i) {
            const int v = tid + (i << 8);
            const int kr = v >> 5;
            const int nc = (v & 31) << 2;
            *(float4*)&Bs[kr][nc] =
                *(const float4*)(B + (size_t)(k0 + kr) * N + bn0 + nc);
        }
        __syncthreads();
        #pragma unroll
        for (int kk = 0; kk < BK; ++kk) {
            float4 a  = *(const float4*)&As[kk][tx << 2];
            float4 b0 = *(const float4*)&Bs[kk][ty << 3];
            float4 b1 = *(const float4*)&Bs[kk][(ty << 3) + 4];
            const float av[4] = {a.x, a.y, a.z, a.w};
            const float bv[8] = {b0.x, b0.y, b0.z, b0.w, b1.x, b1.y, b1.z, b1.w};
            #pragma unroll
            for (int i = 0; i < 4; ++i)
                #pragma unroll
                for (int j = 0; j < 8; ++j)
                    acc[i][j] = fmaf(av[i], bv[j], acc[i][j]);
        }
        __syncthreads();
    }

    #pragma unroll
    for (int i = 0; i < 4; ++i) {
        const int row = bm0 + (tx << 2) + i;
        float* crow = C + (size_t)row * N + bn0 + (ty << 3);
        const float* brow = bias + bn0 + (ty << 3);
        float4 o0 = make_float4(acc[i][0] + brow[0], acc[i][1] + brow[1],
                                acc[i][2] + brow[2], acc[i][3] + brow[3]);
        float4 o1 = make_float4(acc[i][4] + brow[4], acc[i][5] + brow[5],
                                acc[i][6] + brow[6], acc[i][7] + brow[7]);
        *(float4*)crow = o0;
        *(float4*)(crow + 4) = o1;
    }
}

// ---------------- persistent GRU recurrence ----------------
// 256 blocks x 256 threads. Wave wv of block g owns hidden unit nh = g*4+wv;
// its 3 gate columns of W_hh are register-resident (48 floats/lane).
// h rotates through WW+1 slots: slot t+1 written once (sc0 sc1 write-through,
// globally visible pre-barrier), read once at step t+1 with PLAIN CACHED float4
// loads -- safe because no stale copy of a slot line can exist in any L1/L2
// (kernel-start acquire invalidates; afterwards lines are only cached via reads
// issued after the producing store reached the coherence point). 32 blocks/XCD
// then share each line via local L2 instead of hammering the cross-die fabric.
// Barrier: 32 leaf arrival lines (8 blocks each) -> root; globally-last block
// broadcasts the epoch to 32 release lines; each block polls only its own.
__global__ __launch_bounds__(256) void recur_kernel(
    const float* __restrict__ GI, const float* __restrict__ Whh,
    const float* __restrict__ bhh, float* __restrict__ Hm,
    unsigned* __restrict__ bar)
{
    __shared__ __align__(16) float hs[BB][HID];
    const int tid = threadIdx.x;
    const int lane = tid & 63;
    const int wv = tid >> 6;
    const int nh = blockIdx.x * 4 + wv;
    const int leaf_i = blockIdx.x & 31;
    unsigned* leaf = bar + (leaf_i << 5);        // 128B-spaced leaf lines
    unsigned* root = bar + 1024;                 // own line
    unsigned* rel  = bar + 2048 + (leaf_i << 5); // 128B-spaced release lines

    float wr0[16], wr1[16], wr2[16];
    #pragma unroll
    for (int j = 0; j < 4; ++j)
        #pragma unroll
        for (int q = 0; q < 4; ++q) {
            const int k = (j << 8) + (lane << 2) + q;
            const float* wrow = Whh + (size_t)k * G3;
            wr0[(j << 2) + q] = wrow[nh];
            wr1[(j << 2) + q] = wrow[HID + nh];
            wr2[(j << 2) + q] = wrow[2 * HID + nh];
        }
    const float bh0 = bhh[nh];
    const float bh1 = bhh[HID + nh];
    const float bh2 = bhh[2 * HID + nh];

    // prefetch gi for t=0 (lanes 0..7 = batch index)
    float gi_r = 0.f, gi_u = 0.f, gi_n = 0.f;
    if (lane < 8) {
        const float* gp = GI + ((size_t)lane * WW + 0) * G3;
        gi_r = gp[nh];
        gi_u = gp[HID + nh];
        gi_n = gp[2 * HID + nh];
    }

    for (int t = 0; t < WW; ++t) {
        // stage h_{t-1} (slot t) into LDS: plain cached float4 loads (L2-shared)
        {
            const float4* hp = (const float4*)(Hm + (size_t)t * (BB * HID));
            float4* hd = (float4*)hs;
            #pragma unroll
            for (int i = 0; i < 8; ++i)
                hd[tid + (i << 8)] = hp[tid + (i << 8)];
        }
        // prefetch gi for t+1 (h-independent): latency hides under this step
        float gn_r = 0.f, gn_u = 0.f, gn_n = 0.f;
        if (lane < 8 && t + 1 < WW) {
            const float* gp = GI + ((size_t)lane * WW + (t + 1)) * G3;
            gn_r = gp[nh];
            gn_u = gp[HID + nh];
            gn_n = gp[2 * HID + nh];
        }
        __syncthreads();

        float s0 = 0.f, s1 = 0.f, s2 = 0.f;
        #pragma unroll
        for (int b = 0; b < BB; ++b) {
            const float4* hb = (const float4*)&hs[b][0];
            float p0 = 0.f, p1 = 0.f, p2 = 0.f;
            #pragma unroll
            for (int j = 0; j < 4; ++j) {
                float4 h4 = hb[(j << 6) + lane];
                const float hv[4] = {h4.x, h4.y, h4.z, h4.w};
                #pragma unroll
                for (int q = 0; q < 4; ++q) {
                    p0 = fmaf(hv[q], wr0[(j << 2) + q], p0);
                    p1 = fmaf(hv[q], wr1[(j << 2) + q], p1);
                    p2 = fmaf(hv[q], wr2[(j << 2) + q], p2);
                }
            }
            #pragma unroll
            for (int m = 32; m >= 1; m >>= 1) {
                p0 += __shfl_xor(p0, m, 64);
                p1 += __shfl_xor(p1, m, 64);
                p2 += __shfl_xor(p2, m, 64);
            }
            if (lane == b) { s0 = p0; s1 = p1; s2 = p2; }
        }
        // lanes 0..7 apply GRU update for (batch=lane, unit=nh); write-through to L3
        if (lane < 8) {
            const float hold = hs[lane][nh];
            const float r = 1.f / (1.f + expf(-(gi_r + s0 + bh0)));
            const float u = 1.f / (1.f + expf(-(gi_u + s1 + bh1)));
            const float n = tanhf(gi_n + r * (s2 + bh2));
            const float hnew = (1.f - u) * n + u * hold;
            store_dc(Hm + (size_t)(t + 1) * (BB * HID) + lane * HID + nh, hnew);
        }
        __syncthreads();   // s_waitcnt vmcnt(0): all block's h stores are at L3

        if (t < WW - 1) {
            if (tid == 0) {
                unsigned a = __hip_atomic_fetch_add(leaf, 1u, __ATOMIC_RELAXED,
                                                    __HIP_MEMORY_SCOPE_AGENT);
                if ((a & 7u) == 7u) {
                    unsigned r = __hip_atomic_fetch_add(root, 1u, __ATOMIC_RELAXED,
                                                        __HIP_MEMORY_SCOPE_AGENT);
                    if (r == 32u * (unsigned)(t + 1) - 1u) {
                        #pragma unroll
                        for (int i = 0; i < 32; ++i)
                            __hip_atomic_store(bar + 2048 + (i << 5), (unsigned)(t + 1),
                                               __ATOMIC_RELAXED, __HIP_MEMORY_SCOPE_AGENT);
                    }
                }
                while (__hip_atomic_load(rel, __ATOMIC_RELAXED,
                                         __HIP_MEMORY_SCOPE_AGENT) < (unsigned)(t + 1))
                    __builtin_amdgcn_s_sleep(1);
            }
            __syncthreads();
        }
        gi_r = gn_r; gi_u = gn_u; gi_n = gn_n;
    }
}

// ---------------- dense + heads + reparameterized sample ----------------
__global__ __launch_bounds__(128) void head_kernel(
    const float* __restrict__ Hall, const float* __restrict__ Wd,
    const float* __restrict__ bd, const float* __restrict__ Wmu,
    const float* __restrict__ bmu, const float* __restrict__ Wsg,
    const float* __restrict__ bsg, const float* __restrict__ noise,
    float* __restrict__ out)
{
    const int blk = blockIdx.x;        // 0..1023
    const int b = blk >> 7;            // batch
    const int t0 = (blk & 127) << 2;   // 4 timesteps
    __shared__ __align__(16) float hsh[4][HID];
    __shared__ float dsh[4][DN];
    const int tid = threadIdx.x;

    #pragma unroll
    for (int rr = 0; rr < 4; ++rr) {
        const float4* hp = (const float4*)(Hall + (size_t)(t0 + rr) * (BB * HID) + (size_t)b * HID);
        ((float4*)hsh[rr])[tid] = hp[tid];
        ((float4*)hsh[rr])[tid + 128] = hp[tid + 128];
    }
    __syncthreads();

    if (tid < DN) {
        float a0 = bd[tid], a1 = bd[tid], a2 = bd[tid], a3 = bd[tid];
        for (int k = 0; k < HID; ++k) {
            const float wv = Wd[k * DN + tid];
            a0 = fmaf(hsh[0][k], wv, a0);
            a1 = fmaf(hsh[1][k], wv, a1);
            a2 = fmaf(hsh[2][k], wv, a2);
            a3 = fmaf(hsh[3][k], wv, a3);
        }
        dsh[0][tid] = a0; dsh[1][tid] = a1; dsh[2][tid] = a2; dsh[3][tid] = a3;
    }
    __syncthreads();

    if (tid < OD) {
        float mu[4], sg[4];
        #pragma unroll
        for (int rr = 0; rr < 4; ++rr) { mu[rr] = bmu[tid]; sg[rr] = bsg[tid]; }
        for (int i = 0; i < DN; ++i) {
            const float wm = Wmu[i * OD + tid];
            const float ws = Wsg[i * OD + tid];
            #pragma unroll
            for (int rr = 0; rr < 4; ++rr) {
                const float dv = dsh[rr][i];
                mu[rr] = fmaf(dv, wm, mu[rr]);
                sg[rr] = fmaf(dv, ws, sg[rr]);
            }
        }
        #pragma unroll
        for (int rr = 0; rr < 4; ++rr) {
            const float s = sg[rr];
            const float sp = (s > 20.f) ? s : log1pf(expf(s));
            const size_t oi = (size_t)b * (WW * OD) + (size_t)(t0 + rr) * OD + tid;
            out[oi] = mu[rr] + sp * noise[oi];
        }
    }
}

extern "C" void kernel_launch(void* const* d_in, const int* in_sizes, int n_in,
                              void* d_out, int out_size, void* d_ws, size_t ws_size,
                              hipStream_t stream)
{
    const float* z     = (const float*)d_in[0];
    const float* noise = (const float*)d_in[1];
    const float* W_L   = (const float*)d_in[2];
    const float* b_L   = (const float*)d_in[3];
    const float* W_ih  = (const float*)d_in[4];
    const float* b_ih  = (const float*)d_in[5];
    const float* W_hh  = (const float*)d_in[6];
    const float* b_hh  = (const float*)d_in[7];
    const float* W_d   = (const float*)d_in[8];
    const float* b_d   = (const float*)d_in[9];
    const float* W_mu  = (const float*)d_in[10];
    const float* b_mu  = (const float*)d_in[11];
    const float* W_sg  = (const float*)d_in[12];
    const float* b_sg  = (const float*)d_in[13];
    float* out = (float*)d_out;

    float* X    = (float*)d_ws;                      // 4096*4096
    float* GIb  = X + (size_t)ROWS * ZD;             // 4096*3072
    float* Hm   = GIb + (size_t)ROWS * G3;           // (512+1)*8192, slot 0 = h_{-1}=0
    unsigned* bar = (unsigned*)(Hm + (size_t)(WW + 1) * (BB * HID));  // leaves + root + release

    // zero h_{-1} slot and barrier/release lines (d_ws re-poisoned before every launch)
    hipMemsetAsync(Hm, 0, (size_t)(BB * HID) * sizeof(float), stream);
    hipMemsetAsync(bar, 0, 16384, stream);

    // X = Z @ W_lgssm + b_lgssm
    gemm_f32<<<dim3(ZD / BN, ROWS / BM), 256, 0, stream>>>(z, W_L, b_L, X, ROWS, ZD, ZD);
    // GI = X @ W_ih + b_ih
    gemm_f32<<<dim3(G3 / BN, ROWS / BM), 256, 0, stream>>>(X, W_ih, b_ih, GIb, ROWS, G3, ZD);

    // sequential GRU scan (cooperative launch only for the co-residency guarantee)
    void* args[] = { (void*)&GIb, (void*)&W_hh, (void*)&b_hh, (void*)&Hm, (void*)&bar };
    hipLaunchCooperativeKernel((void*)recur_kernel, dim3(HID / 4), dim3(256), args, 0, stream);

    // dense + mu/sigma heads + sample (h_t lives in Hm slot t+1)
    head_kernel<<<dim3(ROWS / 4), 128, 0, stream>>>(Hm + BB * HID, W_d, b_d, W_mu, b_mu, W_sg, b_sg, noise, out);
}